// Round 1
// baseline (175.673 us; speedup 1.0000x reference)
//
#include <hip/hip_runtime.h>
#include <math.h>

// Backflow: out[i] = xi(|x_i|,t)*x_i + sum_j eta(|x_i-x_j|,t)*(x_i-x_j)
// Key transform: t is scalar -> eta(r) is a 1-D scalar function. Build a dense
// lookup table (8193 pts over [0,16], linear interp; f'' ~1e-5 so interp error
// ~1e-11/pair) instead of 1M full MLP evals. xi evaluated directly (1024 evals).

#define TABLE_N 8192
#define RMAX 16.0f
#define NPART 1024

__device__ __forceinline__ float sp(float v) {
    // jax.nn.softplus; inputs here are |v| < ~2, so log1p(exp(v)) is exact enough
    return log1pf(expf(v));
}

// Full MLP: softplus(softplus([r,t]@W1+b1)@W2+b2)@W3+b3, H=64.
// z[m] accumulators so W2 row k (contiguous, wave-uniform address) -> s_load.
__device__ float mlp_scalar(float r, float t,
    const float* __restrict__ W1, const float* __restrict__ b1,
    const float* __restrict__ W2, const float* __restrict__ b2,
    const float* __restrict__ W3, const float* __restrict__ b3)
{
    float z[64];
    #pragma unroll
    for (int m = 0; m < 64; ++m) z[m] = b2[m];
    for (int k = 0; k < 64; ++k) {
        // W1 is (2,64) row-major: W1[0,k]=W1[k], W1[1,k]=W1[64+k]
        float h = sp(fmaf(r, W1[k], fmaf(t, W1[64 + k], b1[k])));
        const float* __restrict__ w2row = W2 + k * 64;
        #pragma unroll
        for (int m = 0; m < 64; ++m) z[m] = fmaf(h, w2row[m], z[m]);
    }
    float o = b3[0];
    #pragma unroll
    for (int m = 0; m < 64; ++m) o = fmaf(sp(z[m]), W3[m], o);
    return o;
}

// blocks 0..32: eta table (8193 entries) -> d_ws
// blocks 33..36: one-body xi term -> d_out (fully initializes d_out)
__global__ __launch_bounds__(256) void k1_table_onebody(
    const float* __restrict__ x, const float* __restrict__ t_ptr,
    const float* __restrict__ xiW1, const float* __restrict__ xib1,
    const float* __restrict__ xiW2, const float* __restrict__ xib2,
    const float* __restrict__ xiW3, const float* __restrict__ xib3,
    const float* __restrict__ eW1,  const float* __restrict__ eb1,
    const float* __restrict__ eW2,  const float* __restrict__ eb2,
    const float* __restrict__ eW3,  const float* __restrict__ eb3,
    float* __restrict__ out, float* __restrict__ table)
{
    const float t = t_ptr[0];
    const int b = blockIdx.x;
    const int tid = threadIdx.x;
    if (b < 33) {
        int idx = b * 256 + tid;
        if (idx <= TABLE_N) {
            float r = (float)idx * (RMAX / (float)TABLE_N);
            table[idx] = mlp_scalar(r, t, eW1, eb1, eW2, eb2, eW3, eb3);
        }
    } else {
        int i = (b - 33) * 256 + tid;  // 0..1023
        float xx = x[3 * i], xy = x[3 * i + 1], xz = x[3 * i + 2];
        float r = sqrtf(fmaf(xx, xx, fmaf(xy, xy, xz * xz)));
        float f = mlp_scalar(r, t, xiW1, xib1, xiW2, xib2, xiW3, xib3);
        out[3 * i]     = f * xx;
        out[3 * i + 1] = f * xy;
        out[3 * i + 2] = f * xz;
    }
}

// One wave per row i; lane handles 16 j's (consecutive j per lane -> conflict-free
// LDS). Diagonal j==i: r=0 -> f*0 = 0, matches reference's eye construction.
__global__ __launch_bounds__(256) void k2_twobody(
    const float* __restrict__ x, const float* __restrict__ table,
    float* __restrict__ out)
{
    __shared__ float xs[NPART], ys[NPART], zs[NPART];
    __shared__ float tab[TABLE_N + 1];
    const int tid = threadIdx.x;

    for (int idx = tid; idx < 3 * NPART; idx += 256) {
        float v = x[idx];
        int j = idx / 3, c = idx - 3 * j;
        if (c == 0) xs[j] = v;
        else if (c == 1) ys[j] = v;
        else zs[j] = v;
    }
    for (int idx = tid; idx <= TABLE_N; idx += 256) tab[idx] = table[idx];
    __syncthreads();

    const int wave = tid >> 6, lane = tid & 63;
    const int i = blockIdx.x * 4 + wave;  // 256 blocks * 4 waves = 1024 rows
    const float xi = xs[i], yi = ys[i], zi = zs[i];
    float ax = 0.f, ay = 0.f, az = 0.f;
    const float scale = (float)TABLE_N / RMAX;  // 512
    #pragma unroll
    for (int it = 0; it < NPART / 64; ++it) {
        int j = it * 64 + lane;
        float dx = xi - xs[j], dy = yi - ys[j], dz = zi - zs[j];
        float r = sqrtf(fmaf(dx, dx, fmaf(dy, dy, dz * dz)));
        float u = fminf(r * scale, (float)TABLE_N - 0.001f);
        int i0 = (int)u;
        float fr = u - (float)i0;
        float t0 = tab[i0], t1 = tab[i0 + 1];
        float f = fmaf(fr, t1 - t0, t0);
        ax = fmaf(f, dx, ax);
        ay = fmaf(f, dy, ay);
        az = fmaf(f, dz, az);
    }
    #pragma unroll
    for (int off = 32; off > 0; off >>= 1) {
        ax += __shfl_xor(ax, off);
        ay += __shfl_xor(ay, off);
        az += __shfl_xor(az, off);
    }
    if (lane == 0) {
        out[3 * i]     += ax;
        out[3 * i + 1] += ay;
        out[3 * i + 2] += az;
    }
}

extern "C" void kernel_launch(void* const* d_in, const int* in_sizes, int n_in,
                              void* d_out, int out_size, void* d_ws, size_t ws_size,
                              hipStream_t stream) {
    const float* x     = (const float*)d_in[0];
    const float* t     = (const float*)d_in[1];
    const float* xiW1  = (const float*)d_in[2];
    const float* xib1  = (const float*)d_in[3];
    const float* xiW2  = (const float*)d_in[4];
    const float* xib2  = (const float*)d_in[5];
    const float* xiW3  = (const float*)d_in[6];
    const float* xib3  = (const float*)d_in[7];
    const float* eW1   = (const float*)d_in[8];
    const float* eb1   = (const float*)d_in[9];
    const float* eW2   = (const float*)d_in[10];
    const float* eb2   = (const float*)d_in[11];
    const float* eW3   = (const float*)d_in[12];
    const float* eb3   = (const float*)d_in[13];
    float* out   = (float*)d_out;
    float* table = (float*)d_ws;  // 8193 floats = 32.8 KB

    k1_table_onebody<<<37, 256, 0, stream>>>(
        x, t, xiW1, xib1, xiW2, xib2, xiW3, xib3,
        eW1, eb1, eW2, eb2, eW3, eb3, out, table);
    k2_twobody<<<256, 256, 0, stream>>>(x, table, out);
}